// Round 5
// baseline (585.989 us; speedup 1.0000x reference)
//
#include <hip/hip_runtime.h>
#include <stdint.h>

// ---- problem constants ----
#define M_ROWS   224        // B*N = 32*7
#define K_DIM    49152      // D_MODEL*PATCH_NUMS
#define NCOL     1344       // 4 bands * 336
#define PRED     336
#define S_CHUNKS 24         // 21*24 = 504 blocks = 2/CU at 512 thr (one round)
#define STEPS    64         // K-steps of 32: 49152/24/32

// ws layout: P (bf16 partials, 14.5 MB) at 0; C (fp32 coeffs, 1.2 MB) at 16 MB;
// Xbf16 (22 MB) at 32 MB
#define C_OFFSET  (16u * 1024u * 1024u)
#define XB_OFFSET (32u * 1024u * 1024u)

typedef __attribute__((ext_vector_type(8))) short short8;
typedef __attribute__((ext_vector_type(4))) float floatx4;

__device__ __forceinline__ uint16_t f32_to_bf16(float f) {
    uint32_t u = __builtin_bit_cast(uint32_t, f);
    uint32_t r = (u + 0x7fffu + ((u >> 16) & 1u)) >> 16;   // RNE
    return (uint16_t)r;
}
__device__ __forceinline__ float bf16_to_f32(uint16_t h) {
    uint32_t u = ((uint32_t)h) << 16;
    return __builtin_bit_cast(float, u);
}
__device__ __forceinline__ uint32_t pack2(float lo, float hi) {
    return (uint32_t)f32_to_bf16(lo) | ((uint32_t)f32_to_bf16(hi) << 16);
}

// ======================= Kernel 0: X fp32 -> bf16 =======================
__global__ __launch_bounds__(256) void cvt_x(
    const float* __restrict__ X, uint16_t* __restrict__ Xb)
{
    const size_t i = ((size_t)blockIdx.x * 256 + threadIdx.x) * 8;
    const float4 a = *(const float4*)(X + i);
    const float4 b = *(const float4*)(X + i + 4);
    uint4 o;
    o.x = pack2(a.x, a.y);
    o.y = pack2(a.z, a.w);
    o.z = pack2(b.x, b.y);
    o.w = pack2(b.z, b.w);
    *(uint4*)(Xb + i) = o;
}

// ============ Kernel 1: split-K GEMM — no LDS, no barriers, 32 waves/CU ============
// 504 blocks x 512 threads. 8 waves as 2 (row-half, 112 rows) x 4 (col-group, 16).
// A-frags: global dwordx4, L1-shared across the 4 col-group waves; XCD swizzle
// (id&7) keeps all 21 ct-blocks of a K-chunk on one XCD (A set 2.75 MB < L2).
// W: strided dwords (64B segments). Register double-buffer, distance-1 prefetch.
__global__ __launch_bounds__(512, 4) void gemm_partial(
    const uint16_t* __restrict__ Xb,  // (224, 49152) bf16
    const float* __restrict__ W,      // (4, 49152, 336) fp32
    uint16_t* __restrict__ P)         // (224, 24, 1344) bf16 partials
{
    const int id = blockIdx.x;
    const int g  = id & 7;                   // presumed XCD
    const int q  = id >> 3;                  // 0..62
    const int ct = q % 21;                   // col-tile 0..20
    const int s  = g + 8 * (q / 21);         // K-chunk 0..23

    const int tid  = threadIdx.x;
    const int lane = tid & 63;
    const int wv   = tid >> 6;               // 0..7
    const int wm   = wv >> 2;                // row-half 0..1
    const int wn   = wv & 3;                 // col-group 0..3
    const int l15  = lane & 15;
    const int kq   = lane >> 4;

    const int c0w  = ct * 64 + wn * 16;      // wave's first flat column
    const int band = c0w / PRED;             // 16 | 336 -> no straddle
    const int p0   = c0w - band * PRED;
    const int kbase = s * (STEPS * 32);

    // W element for lane: W[band][kbase + st*32 + kq*8 + j][p0 + l15]
    const float* wp = W + (size_t)band * ((size_t)K_DIM * PRED)
                        + (size_t)(kbase + kq * 8) * PRED
                        + (size_t)(p0 + l15);
    // A 16B frag for lane, frag f: Xb[wm*112 + 16f + l15][kbase + st*32 + kq*8 ..+8]
    const uint16_t* ap = Xb + (size_t)(wm * 112 + l15) * K_DIM + kbase + kq * 8;

    floatx4 acc[7];
    #pragma unroll
    for (int f = 0; f < 7; ++f) acc[f] = (floatx4){0.f, 0.f, 0.f, 0.f};

    short8 acur[7], anxt[7];
    float  wcur[8], wnxt[8];

    // ---- prologue: step 0 loads ----
    #pragma unroll
    for (int f = 0; f < 7; ++f)
        acur[f] = *(const short8*)(ap + (size_t)(16 * f) * K_DIM);
    #pragma unroll
    for (int j = 0; j < 8; ++j)
        wcur[j] = wp[(size_t)j * PRED];

    #pragma unroll 2
    for (int st = 0; st < STEPS; ++st) {
        // prefetch st+1 into independent regs (no barriers anywhere)
        if (st + 1 < STEPS) {
            const int ko = (st + 1) * 32;
            #pragma unroll
            for (int f = 0; f < 7; ++f)
                anxt[f] = *(const short8*)(ap + (size_t)(16 * f) * K_DIM + ko);
            #pragma unroll
            for (int j = 0; j < 8; ++j)
                wnxt[j] = wp[(size_t)(ko + j) * PRED];
        }

        short8 bfrag;
        #pragma unroll
        for (int j = 0; j < 4; ++j)
            ((uint32_t*)&bfrag)[j] = pack2(wcur[2 * j], wcur[2 * j + 1]);

        #pragma unroll
        for (int f = 0; f < 7; ++f)
            acc[f] = __builtin_amdgcn_mfma_f32_16x16x32_bf16(acur[f], bfrag, acc[f], 0, 0, 0);

        if (st + 1 < STEPS) {
            #pragma unroll
            for (int f = 0; f < 7; ++f) acur[f] = anxt[f];
            #pragma unroll
            for (int j = 0; j < 8; ++j) wcur[j] = wnxt[j];
        }
    }

    // ---- write bf16 partials: C/D layout col=lane&15, row=kq*4+reg ----
    const int col = c0w + l15;
    #pragma unroll
    for (int f = 0; f < 7; ++f) {
        #pragma unroll
        for (int r = 0; r < 4; ++r) {
            const int m = wm * 112 + 16 * f + kq * 4 + r;
            P[((size_t)m * S_CHUNKS + s) * NCOL + col] = f32_to_bf16(acc[f][r]);
        }
    }
}

// ======================= Kernel 2a: sum partials + bias -> C =======================
// 224*1344 = 301056 sums; 1176 blocks x 256, one per thread, fully coalesced.
__global__ __launch_bounds__(256) void reduce_partials(
    const uint16_t* __restrict__ P,    // (224, 24, 1344) bf16
    const float* __restrict__ bias,    // (4, 336) flat == flat col
    float* __restrict__ C)             // (224, 1344) fp32
{
    const int t   = blockIdx.x * 256 + threadIdx.x;   // < 301056
    const int row = t / NCOL;
    const int col = t - row * NCOL;
    const uint16_t* p = P + (size_t)row * S_CHUNKS * NCOL + col;
    float a = bias[col];
    #pragma unroll
    for (int s = 0; s < S_CHUNKS; ++s) a += bf16_to_f32(p[s * NCOL]);
    C[t] = a;
}

// ======================= Kernel 2b: per-row iSWT =======================
__device__ const float REC_LO[8] = {
     0.23037781330885523f,  0.7148465705525415f,   0.6308807679295904f,
    -0.02798376941698385f, -0.18703481171888114f,  0.030841381835986965f,
     0.032883011666982945f, -0.010597401784997278f };
__device__ const float REC_HI[8] = {
     0.010597401784997278f, 0.032883011666982945f, -0.030841381835986965f,
    -0.18703481171888114f,  0.02798376941698385f,   0.6308807679295904f,
    -0.7148465705525415f,   0.23037781330885523f };

__global__ __launch_bounds__(512) void iswt_rows(
    const float* __restrict__ C,       // (224, 1344) fp32
    float* __restrict__ out)           // (224, 336)
{
    __shared__ float coeff[NCOL];
    __shared__ float buf[2][PRED];

    const int row = blockIdx.x;
    const int tid = threadIdx.x;

    for (int c = tid; c < NCOL; c += 512) coeff[c] = C[(size_t)row * NCOL + c];
    __syncthreads();

    if (tid < PRED) buf[0][tid] = coeff[tid];   // band 0 = cA
    __syncthreads();

    int curb = 0;
    for (int j = 3; j >= 1; --j) {
        const int step = 1 << (j - 1);              // 4, 2, 1
        const int M    = PRED / step;               // 84, 168, 336
        const float* cd  = &coeff[(4 - j) * PRED];  // cD3, cD2, cD1
        const float* cur = buf[curb];
        float* nxt       = buf[curb ^ 1];
        if (tid < PRED) {
            const int t = tid;
            const int sidx = t & (step - 1);
            const int m = t / step;
            const int mm1 = (m == 0) ? (M - 1) : (m - 1);
            float x1 = 0.f, x2 = 0.f;
            #pragma unroll
            for (int k = 0; k < 8; ++k) {
                int i1 = m + 3 - k;  if (i1 < 0) i1 += M; else if (i1 >= M) i1 -= M;
                if ((i1 & 1) == 0) {
                    const int pos = i1 * step + sidx;
                    x1 += cur[pos] * REC_LO[k] + cd[pos] * REC_HI[k];
                }
                int i2 = mm1 + 3 - k;  if (i2 < 0) i2 += M; else if (i2 >= M) i2 -= M;
                if ((i2 & 1) == 0) {
                    const int pos = (i2 + 1) * step + sidx;
                    x2 += cur[pos] * REC_LO[k] + cd[pos] * REC_HI[k];
                }
            }
            nxt[t] = 0.5f * (x1 + x2);
        }
        __syncthreads();
        curb ^= 1;
    }

    if (tid < PRED) out[(size_t)row * PRED + tid] = buf[curb][tid];
}

// ======================= launch =======================
extern "C" void kernel_launch(void* const* d_in, const int* in_sizes, int n_in,
                              void* d_out, int out_size, void* d_ws, size_t ws_size,
                              hipStream_t stream) {
    const float* X    = (const float*)d_in[0];   // (224, 49152)
    const float* W    = (const float*)d_in[1];   // (4, 49152, 336)
    const float* bias = (const float*)d_in[2];   // (4, 336)
    float* out        = (float*)d_out;           // (224, 336)
    uint16_t* P       = (uint16_t*)d_ws;
    float*    C       = (float*)((char*)d_ws + C_OFFSET);
    uint16_t* Xb      = (uint16_t*)((char*)d_ws + XB_OFFSET);

    cvt_x          <<<5376, 256, 0, stream>>>(X, Xb);
    gemm_partial   <<<21 * S_CHUNKS, 512, 0, stream>>>(Xb, W, P);
    reduce_partials<<<1176, 256, 0, stream>>>(P, bias, C);
    iswt_rows      <<<M_ROWS, 512, 0, stream>>>(C, out);
}